// Round 7
// baseline (312.718 us; speedup 1.0000x reference)
//
#include <hip/hip_runtime.h>
#include <hip/hip_bf16.h>
#include <math.h>

#define B 16
#define N 512
#define L 512
#define DIM 10
#define DM 128
#define H 8
#define DK 16
#define DFF 512
#define LG 3
#define LO 3
#define NEGV -9.0e15f
#define RF 16     // rows per block (ffn/qkv/oproj)
#define AQR 64    // q-rows per attn block (= lanes per wave)
#define ASEG 8    // key segments (waves) per attn block

__device__ __forceinline__ float wave_reduce_sum(float v) {
    #pragma unroll
    for (int o = 32; o > 0; o >>= 1) v += __shfl_down(v, o, 64);
    return v;
}

__device__ __forceinline__ float dot16(float4 q0, float4 q1, float4 q2, float4 q3,
                                       float4 k0, float4 k1, float4 k2, float4 k3) {
    return q0.x*k0.x + q0.y*k0.y + q0.z*k0.z + q0.w*k0.w
         + q1.x*k1.x + q1.y*k1.y + q1.z*k1.z + q1.w*k1.w
         + q2.x*k2.x + q2.y*k2.y + q2.z*k2.z + q2.w*k2.w
         + q3.x*k3.x + q3.y*k3.y + q3.z*k3.z + q3.w*k3.w;
}

// ---------------- GNN ----------------

__global__ void k_embed_fp(const int* __restrict__ fing, const float* __restrict__ emb_fp,
                           float* __restrict__ xs) {
    int idx = blockIdx.x * blockDim.x + threadIdx.x;
    if (idx >= B * N * DIM) return;
    int d = idx % DIM;
    int bn = idx / DIM;
    xs[idx] = emb_fp[fing[bn] * DIM + d];
}

__global__ void k_gnn_h(const float* __restrict__ xs, const float* __restrict__ fp_mask,
                        const float* __restrict__ Wg, const float* __restrict__ bg,
                        const float* __restrict__ aatt,
                        float* __restrict__ h, float* __restrict__ s1, float* __restrict__ s2) {
    int bn = blockIdx.x * blockDim.x + threadIdx.x;
    if (bn >= B * N) return;
    float x[DIM];
    #pragma unroll
    for (int d = 0; d < DIM; d++) x[d] = xs[bn * DIM + d];
    float m = fp_mask[bn];
    float a1 = 0.f, a2 = 0.f;
    #pragma unroll
    for (int j = 0; j < DIM; j++) {
        float acc = bg[j];
        #pragma unroll
        for (int d = 0; d < DIM; d++) acc += x[d] * Wg[d * DIM + j];
        acc = fmaxf(acc, 0.f) * m;
        h[bn * DIM + j] = acc;
        a1 += acc * aatt[j];
        a2 += acc * aatt[DIM + j];
    }
    s1[bn] = a1;
    s2[bn] = a2;
}

// 16 lane-groups of 16 lanes; each group owns one row. grid = B*(N/16), 256 thr.
__global__ void k_gnn_att(const float* __restrict__ h, const float* __restrict__ s1,
                          const float* __restrict__ s2, const int* __restrict__ adj,
                          float* __restrict__ xs) {
    int b  = blockIdx.x / (N / 16);
    int rg = blockIdx.x % (N / 16);
    int t = threadIdx.x;
    int g  = t >> 4;   // group 0..15
    int ll = t & 15;   // lane in group
    int i = rg * 16 + g;

    __shared__ float h_s[N * DIM];   // 20KB
    __shared__ float s2_s[N];        // 2KB

    const float* hb = h + (long)b * N * DIM;
    for (int idx = t; idx < N * DIM; idx += 256) h_s[idx] = hb[idx];
    for (int j = t; j < N; j += 256) s2_s[j] = s2[b * N + j];
    __syncthreads();

    float s1v = s1[b * N + i];
    const int* adjrow = adj + ((long)b * N + i) * N;

    float e[32];
    #pragma unroll
    for (int c = 0; c < 32; c++) {
        int j = c * 16 + ll;
        float xsc = s1v + s2_s[j];
        xsc = xsc > 0.f ? xsc : 0.01f * xsc;
        e[c] = (adjrow[j] > 0) ? xsc : NEGV;
    }
    float m = e[0];
    #pragma unroll
    for (int c = 1; c < 32; c++) m = fmaxf(m, e[c]);
    #pragma unroll
    for (int off = 1; off < 16; off <<= 1) m = fmaxf(m, __shfl_xor(m, off, 64));

    float sum = 0.f;
    float a[DIM];
    #pragma unroll
    for (int d = 0; d < DIM; d++) a[d] = 0.f;
    #pragma unroll
    for (int c = 0; c < 32; c++) {
        float p = expf(e[c] - m);
        sum += p;
        int j = c * 16 + ll;
        #pragma unroll
        for (int d = 0; d < DIM; d++) a[d] += p * h_s[j * DIM + d];
    }
    #pragma unroll
    for (int off = 1; off < 16; off <<= 1) {
        sum += __shfl_xor(sum, off, 64);
        #pragma unroll
        for (int d = 0; d < DIM; d++) a[d] += __shfl_xor(a[d], off, 64);
    }
    if (ll < DIM) {
        float av = a[0];
        if (ll == 1) av = a[1]; else if (ll == 2) av = a[2]; else if (ll == 3) av = a[3];
        else if (ll == 4) av = a[4]; else if (ll == 5) av = a[5]; else if (ll == 6) av = a[6];
        else if (ll == 7) av = a[7]; else if (ll == 8) av = a[8]; else if (ll == 9) av = a[9];
        xs[((long)b * N + i) * DIM + ll] += av / sum;
    }
}

__global__ void k_compound(const float* __restrict__ xs, const float* __restrict__ fp_mask,
                           const float* __restrict__ Watt, const float* __restrict__ batt,
                           float* __restrict__ compound, float* __restrict__ hc) {
    int b = blockIdx.x;
    int t = threadIdx.x;  // 256
    int wid = t >> 6, lane = t & 63;
    float lacc[DIM];
    #pragma unroll
    for (int d = 0; d < DIM; d++) lacc[d] = 0.f;
    for (int n = t; n < N; n += 256) {
        float m = fp_mask[b * N + n];
        #pragma unroll
        for (int d = 0; d < DIM; d++) lacc[d] += xs[((long)b * N + n) * DIM + d] * m;
    }
    __shared__ float red[4][DIM];
    __shared__ float comp_s[DIM];
    #pragma unroll
    for (int d = 0; d < DIM; d++) lacc[d] = wave_reduce_sum(lacc[d]);
    if (lane == 0) {
        #pragma unroll
        for (int d = 0; d < DIM; d++) red[wid][d] = lacc[d];
    }
    __syncthreads();
    if (t < DIM) {
        float c = (red[0][t] + red[1][t] + red[2][t] + red[3][t]) / (float)N;
        compound[b * DIM + t] = c;
        comp_s[t] = c;
    }
    __syncthreads();
    if (t < DIM) {
        float acc = batt[t];
        #pragma unroll
        for (int e = 0; e < DIM; e++) acc += comp_s[e] * Watt[e * DIM + t];
        hc[b * DIM + t] = fmaxf(acc, 0.f);
    }
}

// ---------------- Transformer ----------------

__global__ void k_pe(float* __restrict__ pe) {
    int idx = blockIdx.x * blockDim.x + threadIdx.x;
    if (idx >= L * DM) return;
    int d = idx % DM, l = idx / DM;
    int k = d >> 1;
    double div = exp((double)(2 * k) * (-log(10000.0) / (double)DM));
    double ang = (double)l * div;
    pe[idx] = (d & 1) ? (float)cos(ang) : (float)sin(ang);
}

__global__ void k_embed_word(const int* __restrict__ words, const float* __restrict__ emb,
                             const float* __restrict__ pe, float* __restrict__ x) {
    long idx = (long)blockIdx.x * blockDim.x + threadIdx.x;
    if (idx >= (long)B * L * DM) return;
    int d = idx % DM;
    long bl = idx / DM;
    int l = (int)(bl % L);
    x[idx] = emb[(long)words[bl] * DM + d] * sqrtf(128.0f) + pe[l * DM + d];
}

__global__ void k_layernorm(const float* __restrict__ x, const float* __restrict__ g,
                            const float* __restrict__ bb, float* __restrict__ out) {
    int row = blockIdx.x;
    int t = threadIdx.x;  // 128
    int wid = t >> 6, lane = t & 63;
    float v = x[(long)row * DM + t];
    float s = wave_reduce_sum(v);
    __shared__ float r2[2], r3[2];
    if (lane == 0) r2[wid] = s;
    __syncthreads();
    float mean = (r2[0] + r2[1]) / (float)DM;
    float dv = v - mean;
    float q = wave_reduce_sum(dv * dv);
    if (lane == 0) r3[wid] = q;
    __syncthreads();
    float sd = sqrtf((r3[0] + r3[1]) / (float)(DM - 1)) + 1e-6f;
    out[(long)row * DM + t] = g[t] * dv / sd + bb[t];
}

// 16 rows per block, 384 threads: thread = (proj, out-col)
__global__ void k_qkv(const float* __restrict__ xn,
                      const float* __restrict__ Wq, const float* __restrict__ bq,
                      const float* __restrict__ Wk, const float* __restrict__ bk,
                      const float* __restrict__ Wv, const float* __restrict__ bv,
                      float* __restrict__ q, float* __restrict__ k, float* __restrict__ v) {
    long row0 = (long)blockIdx.x * RF;
    int t = threadIdx.x;  // 384
    __shared__ float xs_s[RF * DM];
    for (int i = t; i < RF * DM; i += 384) xs_s[i] = xn[row0 * DM + i];
    __syncthreads();
    int proj = t / DM;
    int j = t % DM;
    const float* W    = proj == 0 ? Wq : (proj == 1 ? Wk : Wv);
    const float* bias = proj == 0 ? bq : (proj == 1 ? bk : bv);
    float* out        = proj == 0 ? q  : (proj == 1 ? k  : v);
    float acc[RF];
    #pragma unroll
    for (int r = 0; r < RF; r++) acc[r] = bias[j];
    for (int d = 0; d < DM; d++) {
        float w = W[d * DM + j];
        #pragma unroll
        for (int r = 0; r < RF; r++) acc[r] += xs_s[r * DM + d] * w;
    }
    #pragma unroll
    for (int r = 0; r < RF; r++) {
        long row = row0 + r;
        int b = (int)(row / L), l = (int)(row % L);
        out[(((long)b * H + j / DK) * L + l) * DK + (j % DK)] = acc[r];
    }
}

// broadcast-K flash attention v2. grid = B*H*(L/AQR), 512 threads (8 waves).
// thread = (q-row = lane, key-segment = wave, 64 keys each).
// Chunk = 4 keys; K batch-loaded -> dots -> V batch-loaded -> accumulate.
// All loads broadcast (1 line/instr); launch_bounds(512,2) gives VGPR room
// for whole-chunk batches so latency is paid once per phase, not per load.
__global__ void __launch_bounds__(512, 2)
k_attn(const float* __restrict__ q, const float* __restrict__ k,
       const float* __restrict__ v, const float* __restrict__ wmask,
       float* __restrict__ attnout) {
    int blk = blockIdx.x;
    int qc = blk % (L / AQR);
    int bh = blk / (L / AQR);
    int b = bh / H, hh = bh % H;
    int t = threadIdx.x;   // 512
    int lane = t & 63;     // q-row within block
    int wv = t >> 6;       // key segment (64 keys each)
    int l = qc * AQR + lane;

    const float4* qp = (const float4*)(q + ((long)bh * L + l) * DK);
    float4 q0 = qp[0], q1 = qp[1], q2 = qp[2], q3 = qp[3];
    q0.x*=0.25f;q0.y*=0.25f;q0.z*=0.25f;q0.w*=0.25f;
    q1.x*=0.25f;q1.y*=0.25f;q1.z*=0.25f;q1.w*=0.25f;
    q2.x*=0.25f;q2.y*=0.25f;q2.z*=0.25f;q2.w*=0.25f;
    q3.x*=0.25f;q3.y*=0.25f;q3.z*=0.25f;q3.w*=0.25f;

    const float4* kb4 = (const float4*)(k + (long)bh * L * DK);
    const float4* vb4 = (const float4*)(v + (long)bh * L * DK);
    const float4* wm4 = (const float4*)(wmask + (long)b * L);

    float m = -1e30f, ss = 0.f;
    float4 a0 = make_float4(0,0,0,0), a1 = a0, a2 = a0, a3 = a0;

    for (int c = 0; c < 16; c++) {
        int j0 = wv * 64 + c * 4;
        const float4* kp = kb4 + (long)j0 * 4;
        // K batch (16 float4, independent loads)
        float4 k00=kp[0],  k01=kp[1],  k02=kp[2],  k03=kp[3];
        float4 k10=kp[4],  k11=kp[5],  k12=kp[6],  k13=kp[7];
        float4 k20=kp[8],  k21=kp[9],  k22=kp[10], k23=kp[11];
        float4 k30=kp[12], k31=kp[13], k32=kp[14], k33=kp[15];
        float s0 = dot16(q0,q1,q2,q3, k00,k01,k02,k03);
        float s1 = dot16(q0,q1,q2,q3, k10,k11,k12,k13);
        float s2 = dot16(q0,q1,q2,q3, k20,k21,k22,k23);
        float s3 = dot16(q0,q1,q2,q3, k30,k31,k32,k33);
        float4 wmv = wm4[j0 >> 2];
        s0 = wmv.x > 0.f ? s0 : -1e9f;
        s1 = wmv.y > 0.f ? s1 : -1e9f;
        s2 = wmv.z > 0.f ? s2 : -1e9f;
        s3 = wmv.w > 0.f ? s3 : -1e9f;

        float cm = fmaxf(fmaxf(s0, s1), fmaxf(s2, s3));
        float mn = fmaxf(m, cm);
        float sc = __expf(m - mn);
        m = mn;
        float p0 = __expf(s0 - mn), p1 = __expf(s1 - mn);
        float p2 = __expf(s2 - mn), p3 = __expf(s3 - mn);
        ss = ss * sc + p0 + p1 + p2 + p3;

        // V batch (16 float4)
        const float4* vp = vb4 + (long)j0 * 4;
        float4 v00=vp[0],  v01=vp[1],  v02=vp[2],  v03=vp[3];
        float4 v10=vp[4],  v11=vp[5],  v12=vp[6],  v13=vp[7];
        float4 v20=vp[8],  v21=vp[9],  v22=vp[10], v23=vp[11];
        float4 v30=vp[12], v31=vp[13], v32=vp[14], v33=vp[15];
        a0.x = a0.x*sc + p0*v00.x + p1*v10.x + p2*v20.x + p3*v30.x;
        a0.y = a0.y*sc + p0*v00.y + p1*v10.y + p2*v20.y + p3*v30.y;
        a0.z = a0.z*sc + p0*v00.z + p1*v10.z + p2*v20.z + p3*v30.z;
        a0.w = a0.w*sc + p0*v00.w + p1*v10.w + p2*v20.w + p3*v30.w;
        a1.x = a1.x*sc + p0*v01.x + p1*v11.x + p2*v21.x + p3*v31.x;
        a1.y = a1.y*sc + p0*v01.y + p1*v11.y + p2*v21.y + p3*v31.y;
        a1.z = a1.z*sc + p0*v01.z + p1*v11.z + p2*v21.z + p3*v31.z;
        a1.w = a1.w*sc + p0*v01.w + p1*v11.w + p2*v21.w + p3*v31.w;
        a2.x = a2.x*sc + p0*v02.x + p1*v12.x + p2*v22.x + p3*v32.x;
        a2.y = a2.y*sc + p0*v02.y + p1*v12.y + p2*v22.y + p3*v32.y;
        a2.z = a2.z*sc + p0*v02.z + p1*v12.z + p2*v22.z + p3*v32.z;
        a2.w = a2.w*sc + p0*v02.w + p1*v12.w + p2*v22.w + p3*v32.w;
        a3.x = a3.x*sc + p0*v03.x + p1*v13.x + p2*v23.x + p3*v33.x;
        a3.y = a3.y*sc + p0*v03.y + p1*v13.y + p2*v23.y + p3*v33.y;
        a3.z = a3.z*sc + p0*v03.z + p1*v13.z + p2*v23.z + p3*v33.z;
        a3.w = a3.w*sc + p0*v03.w + p1*v13.w + p2*v23.w + p3*v33.w;
    }

    // merge 8 segment partials via LDS (waves 1-7 publish, wave 0 merges)
    __shared__ float part[ASEG - 1][AQR][19];   // padded to 19 (bank spread)
    if (wv > 0) {
        float* p_ = &part[wv - 1][lane][0];
        p_[0] = m;    p_[1] = ss;
        p_[2] = a0.x; p_[3] = a0.y; p_[4]  = a0.z; p_[5]  = a0.w;
        p_[6] = a1.x; p_[7] = a1.y; p_[8]  = a1.z; p_[9]  = a1.w;
        p_[10]= a2.x; p_[11]= a2.y; p_[12] = a2.z; p_[13] = a2.w;
        p_[14]= a3.x; p_[15]= a3.y; p_[16] = a3.z; p_[17] = a3.w;
    }
    __syncthreads();
    if (wv == 0) {
        #pragma unroll
        for (int s = 0; s < ASEG - 1; s++) {
            const float* p_ = &part[s][lane][0];
            float m2 = p_[0], ss2 = p_[1];
            float mn = fmaxf(m, m2);
            float ea = __expf(m - mn), eb = __expf(m2 - mn);
            ss = ss * ea + ss2 * eb;
            a0.x = a0.x*ea + p_[2]*eb;  a0.y = a0.y*ea + p_[3]*eb;
            a0.z = a0.z*ea + p_[4]*eb;  a0.w = a0.w*ea + p_[5]*eb;
            a1.x = a1.x*ea + p_[6]*eb;  a1.y = a1.y*ea + p_[7]*eb;
            a1.z = a1.z*ea + p_[8]*eb;  a1.w = a1.w*ea + p_[9]*eb;
            a2.x = a2.x*ea + p_[10]*eb; a2.y = a2.y*ea + p_[11]*eb;
            a2.z = a2.z*ea + p_[12]*eb; a2.w = a2.w*ea + p_[13]*eb;
            a3.x = a3.x*ea + p_[14]*eb; a3.y = a3.y*ea + p_[15]*eb;
            a3.z = a3.z*ea + p_[16]*eb; a3.w = a3.w*ea + p_[17]*eb;
            m = mn;
        }
        float inv = 1.f / ss;
        float4* outp = (float4*)(attnout + ((long)b * L + l) * DM + hh * DK);
        outp[0] = make_float4(a0.x*inv, a0.y*inv, a0.z*inv, a0.w*inv);
        outp[1] = make_float4(a1.x*inv, a1.y*inv, a1.z*inv, a1.w*inv);
        outp[2] = make_float4(a2.x*inv, a2.y*inv, a2.z*inv, a2.w*inv);
        outp[3] = make_float4(a3.x*inv, a3.y*inv, a3.z*inv, a3.w*inv);
    }
}

// x += attnout @ Wo + bo ; 16 rows/block, 128 threads
__global__ void k_oproj(const float* __restrict__ attnout, const float* __restrict__ Wo,
                        const float* __restrict__ bo, float* __restrict__ x) {
    long row0 = (long)blockIdx.x * RF;
    int t = threadIdx.x;  // 128
    __shared__ float a_s[RF * DM];
    for (int i = t; i < RF * DM; i += 128) a_s[i] = attnout[row0 * DM + i];
    __syncthreads();
    float acc[RF];
    #pragma unroll
    for (int r = 0; r < RF; r++) acc[r] = bo[t];
    for (int d = 0; d < DM; d++) {
        float w = Wo[d * DM + t];
        #pragma unroll
        for (int r = 0; r < RF; r++) acc[r] += a_s[r * DM + d] * w;
    }
    #pragma unroll
    for (int r = 0; r < RF; r++) x[(row0 + r) * DM + t] += acc[r];
}

// fused FFN: x += relu(xn@W1+b1)@W2+b2 ; 16 rows/block, 512 threads
__global__ void k_ffn(const float* __restrict__ xn, const float* __restrict__ W1,
                      const float* __restrict__ b1, const float* __restrict__ W2,
                      const float* __restrict__ b2, float* __restrict__ x) {
    long row0 = (long)blockIdx.x * RF;
    int t = threadIdx.x;  // 512
    __shared__ float xs_s[RF * DM];    // 8KB
    __shared__ float h_s[RF * DFF];    // 32KB
    for (int i = t; i < RF * DM; i += 512) xs_s[i] = xn[row0 * DM + i];
    __syncthreads();
    {
        float acc[RF];
        #pragma unroll
        for (int r = 0; r < RF; r++) acc[r] = b1[t];
        for (int d = 0; d < DM; d++) {
            float w = W1[d * DFF + t];
            #pragma unroll
            for (int r = 0; r < RF; r++) acc[r] += xs_s[r * DM + d] * w;
        }
        #pragma unroll
        for (int r = 0; r < RF; r++) h_s[r * DFF + t] = fmaxf(acc[r], 0.f);
    }
    __syncthreads();
    int col = t & 127, rq = t >> 7;   // rq uniform per wave
    float acc2[4];
    #pragma unroll
    for (int rr = 0; rr < 4; rr++) acc2[rr] = b2[col];
    for (int f = 0; f < DFF; f++) {
        float w = W2[f * DM + col];
        #pragma unroll
        for (int rr = 0; rr < 4; rr++) acc2[rr] += h_s[(rq * 4 + rr) * DFF + f] * w;
    }
    #pragma unroll
    for (int rr = 0; rr < 4; rr++) x[(row0 + rq * 4 + rr) * DM + col] += acc2[rr];
}

// lnf -> relu -> Wtout -> Watt/relu -> hp ; per row, 128 threads
__global__ void k_lnf_hp(const float* __restrict__ x, const float* __restrict__ g,
                         const float* __restrict__ bb, const float* __restrict__ Wtout,
                         const float* __restrict__ btout, const float* __restrict__ Watt,
                         const float* __restrict__ batt, float* __restrict__ hp) {
    int row = blockIdx.x;
    int t = threadIdx.x;  // 128
    int wid = t >> 6, lane = t & 63;
    float v = x[(long)row * DM + t];
    float s = wave_reduce_sum(v);
    __shared__ float r2[2], r3[2];
    if (lane == 0) r2[wid] = s;
    __syncthreads();
    float mean = (r2[0] + r2[1]) / (float)DM;
    float dv = v - mean;
    float qq = wave_reduce_sum(dv * dv);
    if (lane == 0) r3[wid] = qq;
    __syncthreads();
    float sd = sqrtf((r3[0] + r3[1]) / (float)(DM - 1)) + 1e-6f;
    float xnv = g[t] * dv / sd + bb[t];
    __shared__ float rrelu[DM];
    rrelu[t] = fmaxf(xnv, 0.f);
    __syncthreads();
    __shared__ float wv_s[DIM];
    if (t < DIM) {
        float acc = btout[t];
        for (int d = 0; d < DM; d++) acc += rrelu[d] * Wtout[d * DIM + t];
        wv_s[t] = acc;
    }
    __syncthreads();
    if (t < DIM) {
        float acc = batt[t];
        #pragma unroll
        for (int e = 0; e < DIM; e++) acc += wv_s[e] * Watt[e * DIM + t];
        hp[(long)row * DIM + t] = fmaxf(acc, 0.f);
    }
}

// final: w = tanh(hc . hp_l) ; protein = mean(w * hp) ; 3-layer MLP ; output.
__global__ void k_final(const float* __restrict__ hp, const float* __restrict__ hc,
                        const float* __restrict__ compound, const float* __restrict__ Wout,
                        const float* __restrict__ bout, const float* __restrict__ Wint,
                        const float* __restrict__ bint, float* __restrict__ out) {
    int b = blockIdx.x;
    int t = threadIdx.x;  // 256
    int wid = t >> 6, lane = t & 63;

    __shared__ float wout_s[LO * 2 * DIM * 2 * DIM];  // 1200 floats
    __shared__ float bout_s[LO * 2 * DIM];
    __shared__ float wint_s[2 * DIM * 2];
    __shared__ float bint_s[2];
    __shared__ float hc_s[DIM];
    __shared__ float red[4][DIM];
    __shared__ float cat_s[2 * DIM];
    __shared__ float tmp_s[2 * DIM];

    for (int i = t; i < LO * 2 * DIM * 2 * DIM; i += 256) wout_s[i] = Wout[i];
    for (int i = t; i < LO * 2 * DIM; i += 256) bout_s[i] = bout[i];
    for (int i = t; i < 2 * DIM * 2; i += 256) wint_s[i] = Wint[i];
    if (t < 2) bint_s[t] = bint[t];
    if (t < DIM) hc_s[t] = hc[b * DIM + t];
    __syncthreads();

    float lacc[DIM];
    #pragma unroll
    for (int e = 0; e < DIM; e++) lacc[e] = 0.f;
    for (int l = t; l < L; l += 256) {
        const float* hpl = hp + ((long)b * L + l) * DIM;
        float hv[DIM];
        float dot = 0.f;
        #pragma unroll
        for (int e = 0; e < DIM; e++) { hv[e] = hpl[e]; dot += hc_s[e] * hv[e]; }
        float w = tanhf(dot);
        #pragma unroll
        for (int e = 0; e < DIM; e++) lacc[e] += w * hv[e];
    }
    #pragma unroll
    for (int e = 0; e < DIM; e++) lacc[e] = wave_reduce_sum(lacc[e]);
    if (lane == 0) {
        #pragma unroll
        for (int e = 0; e < DIM; e++) red[wid][e] = lacc[e];
    }
    __syncthreads();
    if (t < DIM) {
        cat_s[t] = compound[b * DIM + t];
        cat_s[DIM + t] = (red[0][t] + red[1][t] + red[2][t] + red[3][t]) / (float)L;
    }
    __syncthreads();

    for (int j = 0; j < LO; j++) {
        float acc = 0.f;
        if (t < 2 * DIM) {
            acc = bout_s[j * 2 * DIM + t];
            #pragma unroll
            for (int e = 0; e < 2 * DIM; e++)
                acc += cat_s[e] * wout_s[j * 2 * DIM * 2 * DIM + e * 2 * DIM + t];
            acc = fmaxf(acc, 0.f);
            tmp_s[t] = acc;
        }
        __syncthreads();
        if (t < 2 * DIM) cat_s[t] = tmp_s[t];
        __syncthreads();
    }
    if (t < 2) {
        float o = bint_s[t];
        #pragma unroll
        for (int e = 0; e < 2 * DIM; e++) o += cat_s[e] * wint_s[e * 2 + t];
        out[b * 2 + t] = o;
    }
}

extern "C" void kernel_launch(void* const* d_in, const int* in_sizes, int n_in,
                              void* d_out, int out_size, void* d_ws, size_t ws_size,
                              hipStream_t stream) {
    (void)in_sizes; (void)n_in; (void)out_size; (void)ws_size;
    const int*   fingerprints = (const int*)d_in[0];
    const float* fp_mask      = (const float*)d_in[1];
    const int*   adjacency    = (const int*)d_in[2];
    const int*   words        = (const int*)d_in[3];
    const float* words_mask   = (const float*)d_in[4];
    const float* emb_fp       = (const float*)d_in[5];
    const float* emb_word     = (const float*)d_in[6];
    const float* Wg   = (const float*)d_in[7];
    const float* bg   = (const float*)d_in[8];
    const float* attn_a = (const float*)d_in[9];
    const float* Wq = (const float*)d_in[10];
    const float* bq = (const float*)d_in[11];
    const float* Wk = (const float*)d_in[12];
    const float* bk = (const float*)d_in[13];
    const float* Wv = (const float*)d_in[14];
    const float* bv = (const float*)d_in[15];
    const float* Wo = (const float*)d_in[16];
    const float* bo = (const float*)d_in[17];
    const float* ln1_g = (const float*)d_in[18];
    const float* ln1_b = (const float*)d_in[19];
    const float* ln2_g = (const float*)d_in[20];
    const float* ln2_b = (const float*)d_in[21];
    const float* lnf_g = (const float*)d_in[22];
    const float* lnf_b = (const float*)d_in[23];
    const float* W1 = (const float*)d_in[24];
    const float* b1 = (const float*)d_in[25];
    const float* W2 = (const float*)d_in[26];
    const float* b2 = (const float*)d_in[27];
    const float* Wtout = (const float*)d_in[28];
    const float* btout = (const float*)d_in[29];
    const float* Watt  = (const float*)d_in[30];
    const float* batt  = (const float*)d_in[31];
    const float* Wout  = (const float*)d_in[32];
    const float* bout  = (const float*)d_in[33];
    const float* Wint  = (const float*)d_in[34];
    const float* bint  = (const float*)d_in[35];
    float* out = (float*)d_out;

    float* w = (float*)d_ws;
    float* xs = w;        w += B * N * DIM;
    float* h  = w;        w += B * N * DIM;
    float* s1 = w;        w += B * N;
    float* s2 = w;        w += B * N;
    float* compound = w;  w += B * DIM;
    float* hc = w;        w += B * DIM;
    float* pe = w;        w += L * DM;
    float* x  = w;        w += (long)B * L * DM;
    float* xn = w;        w += (long)B * L * DM;
    float* qb = w;        w += (long)B * H * L * DK;
    float* kb = w;        w += (long)B * H * L * DK;
    float* vb = w;        w += (long)B * H * L * DK;
    float* attnout = w;   w += (long)B * L * DM;
    float* hp = w;        w += (long)B * L * DIM;

    // ---- GNN ----
    k_embed_fp<<<(B * N * DIM + 255) / 256, 256, 0, stream>>>(fingerprints, emb_fp, xs);
    for (int i = 0; i < LG; i++) {
        k_gnn_h<<<(B * N + 255) / 256, 256, 0, stream>>>(
            xs, fp_mask, Wg + i * DIM * DIM, bg + i * DIM, attn_a + i * 2 * DIM, h, s1, s2);
        k_gnn_att<<<B * (N / 16), 256, 0, stream>>>(h, s1, s2, adjacency, xs);
    }
    k_compound<<<B, 256, 0, stream>>>(xs, fp_mask, Watt, batt, compound, hc);

    // ---- Transformer ----
    k_pe<<<(L * DM + 255) / 256, 256, 0, stream>>>(pe);
    k_embed_word<<<(B * L * DM + 255) / 256, 256, 0, stream>>>(words, emb_word, pe, x);
    k_layernorm<<<B * L, DM, 0, stream>>>(x, ln1_g, ln1_b, xn);
    k_qkv<<<B * L / RF, 3 * DM, 0, stream>>>(xn, Wq, bq, Wk, bk, Wv, bv, qb, kb, vb);
    k_attn<<<B * H * (L / AQR), 512, 0, stream>>>(qb, kb, vb, words_mask, attnout);
    k_oproj<<<B * L / RF, DM, 0, stream>>>(attnout, Wo, bo, x);
    k_layernorm<<<B * L, DM, 0, stream>>>(x, ln2_g, ln2_b, xn);
    k_ffn<<<B * L / RF, DFF, 0, stream>>>(xn, W1, b1, W2, b2, x);
    k_lnf_hp<<<B * L, DM, 0, stream>>>(x, lnf_g, lnf_b, Wtout, btout, Watt, batt, hp);
    k_final<<<B, 256, 0, stream>>>(hp, hc, compound, Wout, bout, Wint, bint, out);
}